// Round 1
// baseline (2793.927 us; speedup 1.0000x reference)
//
#include <hip/hip_runtime.h>

#define NN 100000
#define HH 128
#define EE 1600000
#define LL 2
#define EPSV 0.3f

__global__ void deg_kernel(const int* __restrict__ dst, float* __restrict__ deg) {
    int i = blockIdx.x * blockDim.x + threadIdx.x;
    if (i < EE) atomicAdd(&deg[dst[i]], 1.0f);
}

__global__ void rsqrt_kernel(const float* __restrict__ deg, float* __restrict__ d) {
    int i = blockIdx.x * blockDim.x + threadIdx.x;
    if (i < NN) d[i] = rsqrtf(fmaxf(deg[i], 1.0f));
}

// one wave per node: a_dst[n] = h[n]·w[:H], a_src[n] = h[n]·w[H:]
__global__ void gate_kernel(const float* __restrict__ h, const float* __restrict__ w,
                            float* __restrict__ a_dst, float* __restrict__ a_src) {
    int gtid = blockIdx.x * blockDim.x + threadIdx.x;
    int node = gtid >> 6;
    int lane = threadIdx.x & 63;
    if (node >= NN) return;
    float2 hv = ((const float2*)(h + (size_t)node * HH))[lane];
    float2 w1 = ((const float2*)w)[lane];
    float2 w2 = ((const float2*)(w + HH))[lane];
    float s1 = hv.x * w1.x + hv.y * w1.y;
    float s2 = hv.x * w2.x + hv.y * w2.y;
    #pragma unroll
    for (int off = 32; off > 0; off >>= 1) {
        s1 += __shfl_down(s1, off);
        s2 += __shfl_down(s2, off);
    }
    if (lane == 0) { a_dst[node] = s1; a_src[node] = s2; }
}

// one wave per edge: m[dst] += tanh(a_dst[dst]+a_src[src]+b)*d[dst]*d[src]*h[src]
__global__ void edge_kernel(const int* __restrict__ src, const int* __restrict__ dst,
                            const float* __restrict__ h,
                            const float* __restrict__ a_dst, const float* __restrict__ a_src,
                            const float* __restrict__ d, const float* __restrict__ bias_p,
                            float* __restrict__ m) {
    long long gtid = (long long)blockIdx.x * blockDim.x + threadIdx.x;
    int eid = (int)(gtid >> 6);
    int lane = threadIdx.x & 63;
    if (eid >= EE) return;
    int s = src[eid];
    int t = dst[eid];
    float g = tanhf(a_dst[t] + a_src[s] + bias_p[0]);
    float e = g * d[t] * d[s];
    float2 hv = ((const float2*)(h + (size_t)s * HH))[lane];
    float* mrow = m + (size_t)t * HH + 2 * lane;
    atomicAdd(&mrow[0], e * hv.x);
    atomicAdd(&mrow[1], e * hv.y);
}

__global__ void update_kernel(const float* __restrict__ h_in, float* __restrict__ m,
                              float* __restrict__ h_out) {
    int i = blockIdx.x * blockDim.x + threadIdx.x;
    if (i < NN * HH) {
        float v = EPSV * h_in[i] + m[i];
        h_out[i] = v > 0.0f ? v : 0.0f;
        m[i] = 0.0f;
    }
}

extern "C" void kernel_launch(void* const* d_in, const int* in_sizes, int n_in,
                              void* d_out, int out_size, void* d_ws, size_t ws_size,
                              hipStream_t stream) {
    const float* h0     = (const float*)d_in[0];   // N x H
    const int*   eidx   = (const int*)d_in[1];     // 2 x E
    const float* gate_w = (const float*)d_in[2];   // L x 2H
    const float* gate_b = (const float*)d_in[3];   // L
    (void)in_sizes; (void)n_in; (void)ws_size; (void)out_size;

    const int* src = eidx;
    const int* dst = eidx + EE;

    float* ws   = (float*)d_ws;
    float* deg  = ws;                  // N
    float* dvec = ws + NN;             // N
    float* adst = ws + 2 * NN;         // N
    float* asrc = ws + 3 * NN;         // N
    float* m    = ws + 4 * NN;         // N*H

    float* hbuf = (float*)d_out;

    hipMemsetAsync(deg, 0, NN * sizeof(float), stream);
    hipMemsetAsync(m, 0, (size_t)NN * HH * sizeof(float), stream);

    deg_kernel<<<(EE + 255) / 256, 256, 0, stream>>>(dst, deg);
    rsqrt_kernel<<<(NN + 255) / 256, 256, 0, stream>>>(deg, dvec);

    for (int l = 0; l < LL; ++l) {
        const float* h_in = (l == 0) ? h0 : hbuf;
        const float* wl = gate_w + (size_t)l * 2 * HH;
        const float* bl = gate_b + l;

        {
            int threads = 256;
            int blocks = (NN * 64 + threads - 1) / threads;
            gate_kernel<<<blocks, threads, 0, stream>>>(h_in, wl, adst, asrc);
        }
        {
            long long total = (long long)EE * 64;
            int threads = 256;
            int blocks = (int)((total + threads - 1) / threads);
            edge_kernel<<<blocks, threads, 0, stream>>>(src, dst, h_in, adst, asrc,
                                                        dvec, bl, m);
        }
        {
            int total = NN * HH;
            int threads = 256;
            int blocks = (total + threads - 1) / threads;
            update_kernel<<<blocks, threads, 0, stream>>>(h_in, m, hbuf);
        }
    }
}

// Round 2
// 721.503 us; speedup vs baseline: 3.8724x; 3.8724x over previous
//
#include <hip/hip_runtime.h>

#define NN 100000
#define HH 128
#define EE 1600000
#define LL 2
#define EPSV 0.3f
#define SCAN_B 1024
#define NBLK ((NN + SCAN_B - 1) / SCAN_B)   // 98

// ---- in-degree count (int atomics) ----
__global__ void deg_kernel(const int* __restrict__ dst, int* __restrict__ deg) {
    int i = blockIdx.x * blockDim.x + threadIdx.x;
    if (i < EE) atomicAdd(&deg[dst[i]], 1);
}

// ---- block-level inclusive scan of deg ----
__global__ void scan_block_kernel(const int* __restrict__ deg, int* __restrict__ tmp,
                                  int* __restrict__ bsum) {
    __shared__ int lds[SCAN_B];
    int tid = threadIdx.x;
    int gid = blockIdx.x * SCAN_B + tid;
    int v = (gid < NN) ? deg[gid] : 0;
    lds[tid] = v;
    __syncthreads();
    for (int off = 1; off < SCAN_B; off <<= 1) {
        int t = (tid >= off) ? lds[tid - off] : 0;
        __syncthreads();
        lds[tid] += t;
        __syncthreads();
    }
    if (gid < NN) tmp[gid] = lds[tid];            // inclusive scan within block
    if (tid == SCAN_B - 1) bsum[blockIdx.x] = lds[tid];
}

// ---- single-block exclusive scan of the 98 block sums ----
__global__ void scan_bsum_kernel(int* __restrict__ bsum) {
    __shared__ int lds[128];
    int tid = threadIdx.x;
    int v = (tid < NBLK) ? bsum[tid] : 0;
    lds[tid] = v;
    __syncthreads();
    for (int off = 1; off < 128; off <<= 1) {
        int t = (tid >= off) ? lds[tid - off] : 0;
        __syncthreads();
        lds[tid] += t;
        __syncthreads();
    }
    if (tid < NBLK) bsum[tid] = lds[tid] - v;     // exclusive
}

// ---- offs[i] = exclusive scan; dvec = rsqrt(max(deg,1)); cursor = offs ----
// NOTE: cursor aliases the deg buffer — each thread reads deg[i] before writing.
__global__ void finalize_kernel(const int* __restrict__ tmp, const int* __restrict__ bsum,
                                int* __restrict__ offs, int* __restrict__ deg_cursor,
                                float* __restrict__ dvec) {
    int i = blockIdx.x * blockDim.x + threadIdx.x;
    if (i < NN) {
        int d = deg_cursor[i];
        int off = tmp[i] - d + bsum[i / SCAN_B];
        offs[i] = off;
        dvec[i] = rsqrtf(fmaxf((float)d, 1.0f));
        deg_cursor[i] = off;                      // becomes the scatter cursor
    }
    if (i == 0) offs[NN] = EE;
}

// ---- counting-sort edges by dst: csr_src[pos] = src ----
__global__ void scatter_kernel(const int* __restrict__ src, const int* __restrict__ dst,
                               int* __restrict__ cursor, int* __restrict__ csr_src) {
    int i = blockIdx.x * blockDim.x + threadIdx.x;
    if (i < EE) {
        int pos = atomicAdd(&cursor[dst[i]], 1);
        csr_src[pos] = src[i];
    }
}

// ---- one wave per node: a_dst[n] = h[n]·w[:H], a_src[n] = h[n]·w[H:] ----
__global__ void gate_kernel(const float* __restrict__ h, const float* __restrict__ w,
                            float* __restrict__ a_dst, float* __restrict__ a_src) {
    int gtid = blockIdx.x * blockDim.x + threadIdx.x;
    int node = gtid >> 6;
    int lane = threadIdx.x & 63;
    if (node >= NN) return;
    float2 hv = ((const float2*)(h + (size_t)node * HH))[lane];
    float2 w1 = ((const float2*)w)[lane];
    float2 w2 = ((const float2*)(w + HH))[lane];
    float s1 = hv.x * w1.x + hv.y * w1.y;
    float s2 = hv.x * w2.x + hv.y * w2.y;
    #pragma unroll
    for (int off = 32; off > 0; off >>= 1) {
        s1 += __shfl_down(s1, off);
        s2 += __shfl_down(s2, off);
    }
    if (lane == 0) { a_dst[node] = s1; a_src[node] = s2; }
}

// ---- one wave per dst node: register-accumulate over in-edges, fused update ----
// h_out[t] = relu(EPS*h[t] + sum_j tanh(adst[t]+asrc[s_j]+b)*d[t]*d[s_j]*h[s_j])
__global__ void gather_kernel(const int* __restrict__ csr_src, const int* __restrict__ offs,
                              const float* __restrict__ h,
                              const float* __restrict__ adst, const float* __restrict__ asrc,
                              const float* __restrict__ dvec, const float* __restrict__ bias_p,
                              float* __restrict__ h_out) {
    int node = blockIdx.x * (blockDim.x >> 6) + (threadIdx.x >> 6);
    int lane = threadIdx.x & 63;
    if (node >= NN) return;
    int beg = offs[node];
    int end = offs[node + 1];
    float at = adst[node] + bias_p[0];
    float dt = dvec[node];
    float accx = 0.f, accy = 0.f;
    for (int j = beg; j < end; ++j) {
        int s = csr_src[j];
        float e = tanhf(at + asrc[s]) * dt * dvec[s];
        float2 hv = ((const float2*)(h + (size_t)s * HH))[lane];
        accx += e * hv.x;
        accy += e * hv.y;
    }
    float2 hin = ((const float2*)(h + (size_t)node * HH))[lane];
    float ox = EPSV * hin.x + accx;
    float oy = EPSV * hin.y + accy;
    ((float2*)(h_out + (size_t)node * HH))[lane] = make_float2(fmaxf(ox, 0.f), fmaxf(oy, 0.f));
}

extern "C" void kernel_launch(void* const* d_in, const int* in_sizes, int n_in,
                              void* d_out, int out_size, void* d_ws, size_t ws_size,
                              hipStream_t stream) {
    const float* h0     = (const float*)d_in[0];   // N x H
    const int*   eidx   = (const int*)d_in[1];     // 2 x E
    const float* gate_w = (const float*)d_in[2];   // L x 2H
    const float* gate_b = (const float*)d_in[3];   // L
    (void)in_sizes; (void)n_in; (void)ws_size; (void)out_size;

    const int* src = eidx;
    const int* dst = eidx + EE;

    // workspace layout (4-byte units)
    int*   deg_cursor = (int*)d_ws;                          // N   (deg, then cursor)
    float* dvec       = (float*)d_ws + NN;                   // N
    float* adst       = (float*)d_ws + 2 * (size_t)NN;       // N
    float* asrc       = (float*)d_ws + 3 * (size_t)NN;       // N  (also scan tmp)
    int*   tmp        = (int*)d_ws + 3 * (size_t)NN;         // alias of asrc (pre-layer only)
    int*   offs       = (int*)d_ws + 4 * (size_t)NN;         // N+1
    int*   bsum       = (int*)d_ws + 5 * (size_t)NN + 1;     // 256 (pad)
    int*   csr_src    = (int*)d_ws + 5 * (size_t)NN + 257;   // E
    float* hbuf       = (float*)d_ws + 5 * (size_t)NN + 257 + EE;  // N*H

    hipMemsetAsync(deg_cursor, 0, NN * sizeof(int), stream);

    deg_kernel<<<(EE + 255) / 256, 256, 0, stream>>>(dst, deg_cursor);
    scan_block_kernel<<<NBLK, SCAN_B, 0, stream>>>(deg_cursor, tmp, bsum);
    scan_bsum_kernel<<<1, 128, 0, stream>>>(bsum);
    finalize_kernel<<<(NN + 255) / 256, 256, 0, stream>>>(tmp, bsum, offs, deg_cursor, dvec);
    scatter_kernel<<<(EE + 255) / 256, 256, 0, stream>>>(src, dst, deg_cursor, csr_src);

    for (int l = 0; l < LL; ++l) {
        const float* h_in  = (l == 0) ? h0 : hbuf;
        float*       h_out = (l == LL - 1) ? (float*)d_out : hbuf;
        const float* wl = gate_w + (size_t)l * 2 * HH;
        const float* bl = gate_b + l;

        {
            int threads = 256;
            int blocks = (NN * 64 + threads - 1) / threads;
            gate_kernel<<<blocks, threads, 0, stream>>>(h_in, wl, adst, asrc);
        }
        {
            int threads = 256;                 // 4 waves/block, 1 node/wave
            int blocks = (NN + 3) / 4;
            gather_kernel<<<blocks, threads, 0, stream>>>(csr_src, offs, h_in,
                                                          adst, asrc, dvec, bl, h_out);
        }
    }
}

// Round 3
// 518.523 us; speedup vs baseline: 5.3882x; 1.3915x over previous
//
#include <hip/hip_runtime.h>

#define NN 100000
#define HH 128
#define EE 1600000
#define LL 2
#define EPSV 0.3f
#define SCAN_B 1024
#define NBLK ((NN + SCAN_B - 1) / SCAN_B)   // 98

// ---- in-degree count (int atomics) ----
__global__ void deg_kernel(const int* __restrict__ dst, int* __restrict__ deg) {
    int i = blockIdx.x * blockDim.x + threadIdx.x;
    if (i < EE) atomicAdd(&deg[dst[i]], 1);
}

// ---- block-level inclusive scan of deg ----
__global__ void scan_block_kernel(const int* __restrict__ deg, int* __restrict__ tmp,
                                  int* __restrict__ bsum) {
    __shared__ int lds[SCAN_B];
    int tid = threadIdx.x;
    int gid = blockIdx.x * SCAN_B + tid;
    int v = (gid < NN) ? deg[gid] : 0;
    lds[tid] = v;
    __syncthreads();
    for (int off = 1; off < SCAN_B; off <<= 1) {
        int t = (tid >= off) ? lds[tid - off] : 0;
        __syncthreads();
        lds[tid] += t;
        __syncthreads();
    }
    if (gid < NN) tmp[gid] = lds[tid];            // inclusive scan within block
    if (tid == SCAN_B - 1) bsum[blockIdx.x] = lds[tid];
}

// ---- single-block exclusive scan of the 98 block sums ----
__global__ void scan_bsum_kernel(int* __restrict__ bsum) {
    __shared__ int lds[128];
    int tid = threadIdx.x;
    int v = (tid < NBLK) ? bsum[tid] : 0;
    lds[tid] = v;
    __syncthreads();
    for (int off = 1; off < 128; off <<= 1) {
        int t = (tid >= off) ? lds[tid - off] : 0;
        __syncthreads();
        lds[tid] += t;
        __syncthreads();
    }
    if (tid < NBLK) bsum[tid] = lds[tid] - v;     // exclusive
}

// ---- offs = exclusive scan; dvec = rsqrt(max(deg,1)); cursor = offs ----
__global__ void finalize_kernel(const int* __restrict__ tmp, const int* __restrict__ bsum,
                                int* __restrict__ offs, int* __restrict__ deg_cursor,
                                float* __restrict__ dvec) {
    int i = blockIdx.x * blockDim.x + threadIdx.x;
    if (i < NN) {
        int d = deg_cursor[i];
        int off = tmp[i] - d + bsum[i / SCAN_B];
        offs[i] = off;
        dvec[i] = rsqrtf(fmaxf((float)d, 1.0f));
        deg_cursor[i] = off;                      // becomes the scatter cursor
    }
    if (i == 0) offs[NN] = EE;
}

// ---- counting-sort edges by dst: csr_src[pos] = src, csr_dst[pos] = dst ----
__global__ void scatter_kernel(const int* __restrict__ src, const int* __restrict__ dst,
                               int* __restrict__ cursor, int* __restrict__ csr_src,
                               int* __restrict__ csr_dst) {
    int i = blockIdx.x * blockDim.x + threadIdx.x;
    if (i < EE) {
        int t = dst[i];
        int pos = atomicAdd(&cursor[t], 1);
        csr_src[pos] = src[i];
        csr_dst[pos] = t;
    }
}

// ---- one wave per node: adst[n] = h[n]·w[:H] + bias, asrc[n] = h[n]·w[H:] ----
__global__ void gate_kernel(const float* __restrict__ h, const float* __restrict__ w,
                            const float* __restrict__ bias_p,
                            float* __restrict__ a_dst, float* __restrict__ a_src) {
    int gtid = blockIdx.x * blockDim.x + threadIdx.x;
    int node = gtid >> 6;
    int lane = threadIdx.x & 63;
    if (node >= NN) return;
    float2 hv = ((const float2*)(h + (size_t)node * HH))[lane];
    float2 w1 = ((const float2*)w)[lane];
    float2 w2 = ((const float2*)(w + HH))[lane];
    float s1 = hv.x * w1.x + hv.y * w1.y;
    float s2 = hv.x * w2.x + hv.y * w2.y;
    #pragma unroll
    for (int off = 32; off > 0; off >>= 1) {
        s1 += __shfl_down(s1, off);
        s2 += __shfl_down(s2, off);
    }
    if (lane == 0) { a_dst[node] = s1 + bias_p[0]; a_src[node] = s2; }
}

// ---- per-edge coefficient: e = tanh(adst[t] + asrc[s]) * d[t] * d[s] ----
__global__ void ecoef_kernel(const int* __restrict__ csr_src, const int* __restrict__ csr_dst,
                             const float* __restrict__ adst, const float* __restrict__ asrc,
                             const float* __restrict__ dvec, float* __restrict__ ecoef) {
    int i = blockIdx.x * blockDim.x + threadIdx.x;
    if (i < EE) {
        int s = csr_src[i];
        int t = csr_dst[i];
        ecoef[i] = tanhf(adst[t] + asrc[s]) * dvec[t] * dvec[s];
    }
}

// ---- one wave per dst node; half-wave per edge, float4 rows, unroll x2 ----
__global__ void gather_kernel(const int* __restrict__ csr_src, const int* __restrict__ offs,
                              const float* __restrict__ ecoef,
                              const float* __restrict__ h, float* __restrict__ h_out) {
    int node = blockIdx.x * (blockDim.x >> 6) + (threadIdx.x >> 6);
    int lane = threadIdx.x & 63;
    if (node >= NN) return;
    int half = lane >> 5;      // 0 or 1: which edge of a pair
    int l32  = lane & 31;      // feature quad index (32 x float4 = 128)
    int beg = offs[node];
    int end = offs[node + 1];

    float4 a0 = make_float4(0.f, 0.f, 0.f, 0.f);
    float4 a1 = make_float4(0.f, 0.f, 0.f, 0.f);
    int j = beg + half;
    for (; j + 2 < end; j += 4) {
        int   s0 = csr_src[j];
        int   s1 = csr_src[j + 2];
        float e0 = ecoef[j];
        float e1 = ecoef[j + 2];
        float4 v0 = ((const float4*)(h + (size_t)s0 * HH))[l32];
        float4 v1 = ((const float4*)(h + (size_t)s1 * HH))[l32];
        a0.x += e0 * v0.x; a0.y += e0 * v0.y; a0.z += e0 * v0.z; a0.w += e0 * v0.w;
        a1.x += e1 * v1.x; a1.y += e1 * v1.y; a1.z += e1 * v1.z; a1.w += e1 * v1.w;
    }
    for (; j < end; j += 2) {
        int   s0 = csr_src[j];
        float e0 = ecoef[j];
        float4 v0 = ((const float4*)(h + (size_t)s0 * HH))[l32];
        a0.x += e0 * v0.x; a0.y += e0 * v0.y; a0.z += e0 * v0.z; a0.w += e0 * v0.w;
    }
    a0.x += a1.x; a0.y += a1.y; a0.z += a1.z; a0.w += a1.w;
    // combine the two half-wave partial sums (lane ^ 32)
    a0.x += __shfl_xor(a0.x, 32);
    a0.y += __shfl_xor(a0.y, 32);
    a0.z += __shfl_xor(a0.z, 32);
    a0.w += __shfl_xor(a0.w, 32);
    if (half == 0) {
        float4 hin = ((const float4*)(h + (size_t)node * HH))[l32];
        float4 o;
        o.x = fmaxf(EPSV * hin.x + a0.x, 0.f);
        o.y = fmaxf(EPSV * hin.y + a0.y, 0.f);
        o.z = fmaxf(EPSV * hin.z + a0.z, 0.f);
        o.w = fmaxf(EPSV * hin.w + a0.w, 0.f);
        ((float4*)(h_out + (size_t)node * HH))[l32] = o;
    }
}

extern "C" void kernel_launch(void* const* d_in, const int* in_sizes, int n_in,
                              void* d_out, int out_size, void* d_ws, size_t ws_size,
                              hipStream_t stream) {
    const float* h0     = (const float*)d_in[0];   // N x H
    const int*   eidx   = (const int*)d_in[1];     // 2 x E
    const float* gate_w = (const float*)d_in[2];   // L x 2H
    const float* gate_b = (const float*)d_in[3];   // L
    (void)in_sizes; (void)n_in; (void)ws_size; (void)out_size;

    const int* src = eidx;
    const int* dst = eidx + EE;

    // workspace layout (4-byte units)
    int*   deg_cursor = (int*)d_ws;                                   // N (deg, then cursor)
    float* dvec       = (float*)d_ws + NN;                            // N
    float* adst       = (float*)d_ws + 2 * (size_t)NN;                // N
    float* asrc       = (float*)d_ws + 3 * (size_t)NN;                // N (aliases scan tmp)
    int*   tmp        = (int*)d_ws + 3 * (size_t)NN;                  // alias (prep only)
    int*   offs       = (int*)d_ws + 4 * (size_t)NN;                  // N+1
    int*   bsum       = (int*)d_ws + 5 * (size_t)NN + 1;              // 256 (pad)
    int*   csr_src    = (int*)d_ws + 5 * (size_t)NN + 257;            // E
    int*   csr_dst    = (int*)d_ws + 5 * (size_t)NN + 257 + EE;       // E
    float* ecoef      = (float*)d_ws + 5 * (size_t)NN + 257 + 2 * (size_t)EE;  // E
    float* hbuf       = (float*)d_ws + 5 * (size_t)NN + 257 + 3 * (size_t)EE;  // N*H

    hipMemsetAsync(deg_cursor, 0, NN * sizeof(int), stream);

    deg_kernel<<<(EE + 255) / 256, 256, 0, stream>>>(dst, deg_cursor);
    scan_block_kernel<<<NBLK, SCAN_B, 0, stream>>>(deg_cursor, tmp, bsum);
    scan_bsum_kernel<<<1, 128, 0, stream>>>(bsum);
    finalize_kernel<<<(NN + 255) / 256, 256, 0, stream>>>(tmp, bsum, offs, deg_cursor, dvec);
    scatter_kernel<<<(EE + 255) / 256, 256, 0, stream>>>(src, dst, deg_cursor, csr_src, csr_dst);

    for (int l = 0; l < LL; ++l) {
        const float* h_in  = (l == 0) ? h0 : hbuf;
        float*       h_out = (l == LL - 1) ? (float*)d_out : hbuf;
        const float* wl = gate_w + (size_t)l * 2 * HH;
        const float* bl = gate_b + l;

        {
            int threads = 256;
            int blocks = (NN * 64 + threads - 1) / threads;
            gate_kernel<<<blocks, threads, 0, stream>>>(h_in, wl, bl, adst, asrc);
        }
        {
            int threads = 256;
            int blocks = (EE + threads - 1) / threads;
            ecoef_kernel<<<blocks, threads, 0, stream>>>(csr_src, csr_dst, adst, asrc,
                                                         dvec, ecoef);
        }
        {
            int threads = 256;                 // 4 waves/block, 1 node/wave
            int blocks = (NN + 3) / 4;
            gather_kernel<<<blocks, threads, 0, stream>>>(csr_src, offs, ecoef, h_in, h_out);
        }
    }
}